// Round 10
// baseline (401.449 us; speedup 1.0000x reference)
//
#include <hip/hip_runtime.h>
#include <hip/hip_bf16.h>

typedef __attribute__((ext_vector_type(8))) short bf16x8;
typedef __attribute__((ext_vector_type(4))) short short4v;
typedef __attribute__((ext_vector_type(4))) float floatx4;

#define MFMA16(A, B, C) __builtin_amdgcn_mfma_f32_16x16x32_bf16((A), (B), (C), 0, 0, 0)

__device__ inline short bf16bits(float f) {
  __hip_bfloat16 h = __float2bfloat16(f);
  return *reinterpret_cast<short*>(&h);
}
// HW packed f32->bf16 (RNE). No builtin on gfx950 (m240) -> inline asm.
__device__ inline unsigned cvtpk(float lo, float hi) {
  unsigned r;
  asm("v_cvt_pk_bf16_f32 %0, %1, %2" : "=v"(r) : "v"(lo), "v"(hi));
  return r;
}
typedef __attribute__((address_space(3))) char lds_char;
typedef __attribute__((address_space(1))) const char glob_char;
__device__ inline void gll16(const void* g, void* l) {
  __builtin_amdgcn_global_load_lds((glob_char*)g, (lds_char*)l, 16, 0, 0);
}

// ---------------------------------------------------------------------------
// Round 10: LN parts rewritten wave-per-row (no barrier/LDS; shfl_xor
// butterfly; cvtpk stores). Block = 4 rows. LN grid 4096 -> 1024.
// Merged ln1 + wqkv transpose: grid 1792 (1024 LN + 768 transpose).
// ---------------------------------------------------------------------------
__global__ __launch_bounds__(256) void ln_qkvtrans_kernel(
    const float* __restrict__ x, __hip_bfloat16* __restrict__ y,
    const float* __restrict__ alpha_p, const float* __restrict__ bias_p,
    const float* __restrict__ wq, const float* __restrict__ wk,
    const float* __restrict__ wv, __hip_bfloat16* __restrict__ wqkvT) {
  __shared__ __align__(16) __hip_bfloat16 tile[64][72];
  const int bid = blockIdx.x;
  const int t = threadIdx.x;
  if (bid < 1024) {
    const int wvv = t >> 6, lane = t & 63;
    const long row = (long)bid * 4 + wvv;
    const float* xr = x + row * 1024;
    float4 v4[4];
#pragma unroll
    for (int i = 0; i < 4; i++) v4[i] = *(const float4*)&xr[lane * 4 + i * 256];
    float sum = 0.f, sq = 0.f;
#pragma unroll
    for (int i = 0; i < 4; i++) {
      sum += (v4[i].x + v4[i].y) + (v4[i].z + v4[i].w);
      sq += (v4[i].x * v4[i].x + v4[i].y * v4[i].y) +
            (v4[i].z * v4[i].z + v4[i].w * v4[i].w);
    }
#pragma unroll
    for (int off = 32; off; off >>= 1) {
      sum += __shfl_xor(sum, off);
      sq += __shfl_xor(sq, off);
    }
    const float mean = sum * (1.f / 1024.f);
    float var = (sq - 1024.f * mean * mean) * (1.f / 1023.f);
    var = fmaxf(var, 0.f);
    const float denom = sqrtf(var) + 1e-5f;
    const float sc = alpha_p[0] / denom;
    const float beta = bias_p[0];
    __hip_bfloat16* yr = y + row * 1024;
#pragma unroll
    for (int i = 0; i < 4; i++) {
      uint2 st;
      st.x = cvtpk((v4[i].x - mean) * sc + beta, (v4[i].y - mean) * sc + beta);
      st.y = cvtpk((v4[i].z - mean) * sc + beta, (v4[i].w - mean) * sc + beta);
      *(uint2*)&yr[lane * 4 + i * 256] = st;
    }
  } else {
    const int tt = bid - 1024;
    const int which = tt >> 8;
    const float* src = which == 0 ? wq : (which == 1 ? wk : wv);
    __hip_bfloat16* dst = wqkvT + (size_t)which * 1024 * 1024;
    const long r0 = (long)((tt >> 4) & 15) * 64, c0 = (long)(tt & 15) * 64;
    for (int i = t; i < 1024; i += 256) {
      int r = i >> 4, c4 = (i & 15) * 4;
      float4 f = *(const float4*)&src[(r0 + r) * 1024 + c0 + c4];
      short4v s;
      s[0] = bf16bits(f.x); s[1] = bf16bits(f.y);
      s[2] = bf16bits(f.z); s[3] = bf16bits(f.w);
      *(short4v*)&tile[r][c4] = s;
    }
    __syncthreads();
    for (int i = t; i < 512; i += 256) {
      int c = i >> 3, r8 = (i & 7) * 8;
      bf16x8 sv;
#pragma unroll
      for (int j = 0; j < 8; j++) sv[j] = *reinterpret_cast<const short*>(&tile[r8 + j][c]);
      *(bf16x8*)&dst[(c0 + c) * 1024 + r0 + r8] = sv;
    }
  }
}

// ---------------------------------------------------------------------------
// Merged stage-B prep kernel (round 6).
// ---------------------------------------------------------------------------
__global__ __launch_bounds__(256) void prep_kernel(
    const __hip_bfloat16* __restrict__ qkv, __hip_bfloat16* __restrict__ vt,
    const float* __restrict__ wo, __hip_bfloat16* __restrict__ woT,
    const int* __restrict__ mask, float* __restrict__ addm,
    int* __restrict__ flags) {
  __shared__ __align__(16) __hip_bfloat16 tile[64][72];
  __shared__ int ok[4];
  const int bid = blockIdx.x;
  if (bid < 1024) {
    const int bh = bid >> 5, b = bh >> 4, h = bh & 15;
    const long s0 = (long)(bid & 31) * 64;
    const __hip_bfloat16* src = qkv + ((long)b * 2048 + s0) * 3072 + 2048 + h * 64;
    for (int i = threadIdx.x; i < 512; i += 256) {
      int s = i >> 3, d8 = (i & 7) * 8;
      *(uint4*)&tile[s][d8] = *(const uint4*)&src[(long)s * 3072 + d8];
    }
    __syncthreads();
    __hip_bfloat16* dstb = vt + (long)bh * 64 * 2048 + s0;
    for (int i = threadIdx.x; i < 512; i += 256) {
      int d = i >> 3, s8 = (i & 7) * 8;
      bf16x8 sv;
#pragma unroll
      for (int j = 0; j < 8; j++) sv[j] = *reinterpret_cast<const short*>(&tile[s8 + j][d]);
      *(bf16x8*)&dstb[(long)d * 2048 + s8] = sv;
    }
  } else if (bid < 1280) {
    const int t = bid - 1024;
    const long r0 = (long)(t >> 4) * 64, c0 = (long)(t & 15) * 64;
    for (int i = threadIdx.x; i < 1024; i += 256) {
      int r = i >> 4, c4 = (i & 15) * 4;
      float4 f = *(const float4*)&wo[(r0 + r) * 1024 + c0 + c4];
      short4v s;
      s[0] = bf16bits(f.x); s[1] = bf16bits(f.y);
      s[2] = bf16bits(f.z); s[3] = bf16bits(f.w);
      *(short4v*)&tile[r][c4] = s;
    }
    __syncthreads();
    for (int i = threadIdx.x; i < 512; i += 256) {
      int c = i >> 3, r8 = (i & 7) * 8;
      bf16x8 sv;
#pragma unroll
      for (int j = 0; j < 8; j++) sv[j] = *reinterpret_cast<const short*>(&tile[r8 + j][c]);
      *(bf16x8*)&woT[(c0 + c) * 1024 + r0 + r8] = sv;
    }
  } else {
    const int i = (bid - 1280) * 256 + threadIdx.x;
    const int mv = mask[i];
    addm[i] = mv ? 0.f : -1e30f;
    const unsigned long long bal = __ballot(mv != 0);
    if ((threadIdx.x & 63) == 0) ok[threadIdx.x >> 6] = (bal == ~0ull) ? 1 : 0;
    __syncthreads();
    if (threadIdx.x == 0) flags[bid - 1280] = ok[0] & ok[1] & ok[2] & ok[3];
  }
}

// ---------------------------------------------------------------------------
// Round 10: merged ln2 + wtrans(c=0), LN wave-per-row. Grid 2048
// (1024 LN + 1024 transpose).
// ---------------------------------------------------------------------------
__global__ __launch_bounds__(256) void ln2_wtrans_kernel(
    const float* __restrict__ x1, __hip_bfloat16* __restrict__ xn2,
    const float* __restrict__ alpha_p, const float* __restrict__ bias_p,
    const float* __restrict__ w1c, const float* __restrict__ w2c,
    __hip_bfloat16* __restrict__ w1Th, __hip_bfloat16* __restrict__ w2Th) {
  __shared__ __align__(16) __hip_bfloat16 tile[64][72];
  const int bid = blockIdx.x;
  const int t = threadIdx.x;
  if (bid < 1024) {
    const int wvv = t >> 6, lane = t & 63;
    const long row = (long)bid * 4 + wvv;
    const float* xr = x1 + row * 1024;
    float4 v4[4];
#pragma unroll
    for (int i = 0; i < 4; i++) v4[i] = *(const float4*)&xr[lane * 4 + i * 256];
    float sum = 0.f, sq = 0.f;
#pragma unroll
    for (int i = 0; i < 4; i++) {
      sum += (v4[i].x + v4[i].y) + (v4[i].z + v4[i].w);
      sq += (v4[i].x * v4[i].x + v4[i].y * v4[i].y) +
            (v4[i].z * v4[i].z + v4[i].w * v4[i].w);
    }
#pragma unroll
    for (int off = 32; off; off >>= 1) {
      sum += __shfl_xor(sum, off);
      sq += __shfl_xor(sq, off);
    }
    const float mean = sum * (1.f / 1024.f);
    float var = (sq - 1024.f * mean * mean) * (1.f / 1023.f);
    var = fmaxf(var, 0.f);
    const float denom = sqrtf(var) + 1e-5f;
    const float sc = alpha_p[0] / denom;
    const float beta = bias_p[0];
    __hip_bfloat16* yr = xn2 + row * 1024;
#pragma unroll
    for (int i = 0; i < 4; i++) {
      uint2 st;
      st.x = cvtpk((v4[i].x - mean) * sc + beta, (v4[i].y - mean) * sc + beta);
      st.y = cvtpk((v4[i].z - mean) * sc + beta, (v4[i].w - mean) * sc + beta);
      *(uint2*)&yr[lane * 4 + i * 256] = st;
    }
  } else {
    const int wb = bid - 1024;
    const float* src;
    __hip_bfloat16* dst;
    int R, ldS;
    long r0, c0;
    if (wb < 512) {
      src = w1c; dst = w1Th; R = 1024; ldS = 4096;
      r0 = (long)(wb >> 5) * 64; c0 = (long)(wb & 31) * 64;
    } else {
      const int t2 = wb - 512;
      src = w2c; dst = w2Th; R = 2048; ldS = 1024;
      r0 = (long)(t2 >> 4) * 64; c0 = (long)(t2 & 15) * 64;
    }
    for (int i = t; i < 1024; i += 256) {
      int r = i >> 4, c4 = (i & 15) * 4;
      float4 f = *(const float4*)&src[(r0 + r) * ldS + c0 + c4];
      short4v s;
      s[0] = bf16bits(f.x); s[1] = bf16bits(f.y);
      s[2] = bf16bits(f.z); s[3] = bf16bits(f.w);
      *(short4v*)&tile[r][c4] = s;
    }
    __syncthreads();
    for (int i = t; i < 512; i += 256) {
      int c = i >> 3, r8 = (i & 7) * 8;
      bf16x8 sv;
#pragma unroll
      for (int j = 0; j < 8; j++) sv[j] = *reinterpret_cast<const short*>(&tile[r8 + j][c]);
      *(bf16x8*)&dst[(c0 + c) * R + r0 + r8] = sv;
    }
  }
}

// ---------------------------------------------------------------------------
// Merged per-half FFN weight transpose (round 6) — used for c=1.
// ---------------------------------------------------------------------------
__global__ __launch_bounds__(256) void wtrans_kernel(
    const float* __restrict__ w1c, const float* __restrict__ w2c,
    __hip_bfloat16* __restrict__ w1Th, __hip_bfloat16* __restrict__ w2Th) {
  __shared__ __align__(16) __hip_bfloat16 tile[64][72];
  const int bid = blockIdx.x;
  const float* src;
  __hip_bfloat16* dst;
  int R, ldS;
  long r0, c0;
  if (bid < 512) {
    src = w1c; dst = w1Th; R = 1024; ldS = 4096;
    r0 = (long)(bid >> 5) * 64; c0 = (long)(bid & 31) * 64;
  } else {
    const int t = bid - 512;
    src = w2c; dst = w2Th; R = 2048; ldS = 1024;
    r0 = (long)(t >> 4) * 64; c0 = (long)(t & 15) * 64;
  }
  for (int i = threadIdx.x; i < 1024; i += 256) {
    int r = i >> 4, c4 = (i & 15) * 4;
    float4 f = *(const float4*)&src[(r0 + r) * ldS + c0 + c4];
    short4v s;
    s[0] = bf16bits(f.x); s[1] = bf16bits(f.y);
    s[2] = bf16bits(f.z); s[3] = bf16bits(f.w);
    *(short4v*)&tile[r][c4] = s;
  }
  __syncthreads();
  for (int i = threadIdx.x; i < 512; i += 256) {
    int c = i >> 3, r8 = (i & 7) * 8;
    bf16x8 sv;
#pragma unroll
    for (int j = 0; j < 8; j++) sv[j] = *reinterpret_cast<const short*>(&tile[r8 + j][c]);
    *(bf16x8*)&dst[(c0 + c) * R + r0 + r8] = sv;
  }
}

// ---------------------------------------------------------------------------
// d_out = x1 + b2 (broadcast over rows), fp32
// ---------------------------------------------------------------------------
__global__ __launch_bounds__(256) void bias_add_kernel(
    const float* __restrict__ x1, const float* __restrict__ b2,
    float* __restrict__ out) {
  const int i = (blockIdx.x * 256 + threadIdx.x) * 4;
  float4 v = *(const float4*)&x1[i];
  const float4 bb = *(const float4*)&b2[i & 1023];
  v.x += bb.x; v.y += bb.y; v.z += bb.z; v.w += bb.w;
  *(float4*)&out[i] = v;
}

// ---------------------------------------------------------------------------
// bf16 GEMM, B pre-transposed: 128x128 tile, BK=32, dbuf + XCD swizzle.
// Used for the qkv GEMM (3 blocks/CU).
// ---------------------------------------------------------------------------
template <int EPI>
__global__ __launch_bounds__(256) void gemm_bt_kernel(
    const __hip_bfloat16* __restrict__ A, const __hip_bfloat16* __restrict__ Bt,
    void* __restrict__ Cv, const float* __restrict__ bias,
    const float* __restrict__ res, int M, int N, int K) {
  __shared__ __align__(16) __hip_bfloat16 lA[2][128 * 32];
  __shared__ __align__(16) __hip_bfloat16 lB[2][128 * 32];
  const int tid = threadIdx.x;
  const int wave = tid >> 6, lane = tid & 63;
  const int quad = lane >> 4, l16 = lane & 15;
  const int wm = wave >> 1, wn = wave & 1;

  const int gx = gridDim.x;
  const int nwg = gx * gridDim.y;
  int bid = blockIdx.y * gx + blockIdx.x;
  bid = (bid & 7) * (nwg >> 3) + (bid >> 3);
  const long m0 = (long)(bid / gx) * 128;
  const long n0 = (long)(bid % gx) * 128;

  const int rA0 = tid >> 2, cA0 = (tid & 3) * 8;
  const int rA1 = (tid + 256) >> 2, cA1 = ((tid + 256) & 3) * 8;

  floatx4 acc[4][4];
#pragma unroll
  for (int i = 0; i < 4; i++)
#pragma unroll
    for (int j = 0; j < 4; j++) acc[i][j] = (floatx4){0.f, 0.f, 0.f, 0.f};

  const __hip_bfloat16* Ab = A + m0 * K;
  const __hip_bfloat16* Bb = Bt + n0 * K;

  gll16(&Ab[(long)rA0 * K + cA0], &lA[0][wave * 512]);
  gll16(&Ab[(long)rA1 * K + cA1], &lA[0][2048 + wave * 512]);
  gll16(&Bb[(long)rA0 * K + cA0], &lB[0][wave * 512]);
  gll16(&Bb[(long)rA1 * K + cA1], &lB[0][2048 + wave * 512]);

  int cur = 0;
  for (int k0 = 0; k0 < K; k0 += 32) {
    __syncthreads();
    if (k0 + 32 < K) {
      const int nxt = cur ^ 1;
      gll16(&Ab[(long)rA0 * K + k0 + 32 + cA0], &lA[nxt][wave * 512]);
      gll16(&Ab[(long)rA1 * K + k0 + 32 + cA1], &lA[nxt][2048 + wave * 512]);
      gll16(&Bb[(long)rA0 * K + k0 + 32 + cA0], &lB[nxt][wave * 512]);
      gll16(&Bb[(long)rA1 * K + k0 + 32 + cA1], &lB[nxt][2048 + wave * 512]);
    }
    bf16x8 af[4], bfr[4];
#pragma unroll
    for (int mi = 0; mi < 4; mi++)
      af[mi] = *(const bf16x8*)&lA[cur][(wm * 64 + mi * 16 + l16) * 32 + quad * 8];
#pragma unroll
    for (int ni = 0; ni < 4; ni++)
      bfr[ni] = *(const bf16x8*)&lB[cur][(wn * 64 + ni * 16 + l16) * 32 + quad * 8];
#pragma unroll
    for (int mi = 0; mi < 4; mi++)
#pragma unroll
      for (int ni = 0; ni < 4; ni++)
        acc[mi][ni] = MFMA16(af[mi], bfr[ni], acc[mi][ni]);
    cur ^= 1;
  }

#pragma unroll
  for (int mi = 0; mi < 4; mi++) {
#pragma unroll
    for (int ni = 0; ni < 4; ni++) {
#pragma unroll
      for (int r = 0; r < 4; r++) {
        const long row = m0 + wm * 64 + mi * 16 + quad * 4 + r;
        const long col = n0 + wn * 64 + ni * 16 + l16;
        const long idx = row * N + col;
        float v = acc[mi][ni][r];
        if (EPI == 0) {
          ((__hip_bfloat16*)Cv)[idx] = __float2bfloat16(v);
        } else if (EPI == 1) {
          ((float*)Cv)[idx] = v + res[idx];
        } else if (EPI == 2) {
          v += bias[col];
          ((__hip_bfloat16*)Cv)[idx] = __float2bfloat16(fmaxf(v, 0.f));
        } else if (EPI == 3) {
          float* Cf = (float*)Cv;
          Cf[idx] = Cf[idx] + v;
        }
      }
    }
  }
}

// ---------------------------------------------------------------------------
// 128x128 tile, BK=64, XOR-swizzled LDS (round 7). Used for ffn1 only.
// ---------------------------------------------------------------------------
template <int EPI>
__global__ __launch_bounds__(256) void gemm_bt_k64_kernel(
    const __hip_bfloat16* __restrict__ A, const __hip_bfloat16* __restrict__ Bt,
    void* __restrict__ Cv, const float* __restrict__ bias,
    const float* __restrict__ res, int M, int N, int K) {
  __shared__ __align__(16) __hip_bfloat16 lA[2][128 * 64];
  __shared__ __align__(16) __hip_bfloat16 lB[2][128 * 64];
  const int tid = threadIdx.x;
  const int wave = tid >> 6, lane = tid & 63;
  const int quad = lane >> 4, l16 = lane & 15;
  const int wm = wave >> 1, wn = wave & 1;

  const int gx = gridDim.x;
  const int nwg = gx * gridDim.y;
  int bid = blockIdx.y * gx + blockIdx.x;
  bid = (bid & 7) * (nwg >> 3) + (bid >> 3);
  const long m0 = (long)(bid / gx) * 128;
  const long n0 = (long)(bid % gx) * 128;

  const int srow = lane >> 3;               // row within 8-row chunk
  const int cg = (lane & 7) ^ srow;         // pre-swizzled global k-group

  floatx4 acc[4][4];
#pragma unroll
  for (int i = 0; i < 4; i++)
#pragma unroll
    for (int j = 0; j < 4; j++) acc[i][j] = (floatx4){0.f, 0.f, 0.f, 0.f};

  const __hip_bfloat16* Ab = A + m0 * K;
  const __hip_bfloat16* Bb = Bt + n0 * K;

#pragma unroll
  for (int j = 0; j < 4; ++j) {
    const int c = wave + j * 4;
    gll16(&Ab[(long)(c * 8 + srow) * K + cg * 8], &lA[0][c * 512]);
    gll16(&Bb[(long)(c * 8 + srow) * K + cg * 8], &lB[0][c * 512]);
  }

  int cur = 0;
  for (int k0 = 0; k0 < K; k0 += 64) {
    __syncthreads();
    if (k0 + 64 < K) {
      const int nxt = cur ^ 1;
#pragma unroll
      for (int j = 0; j < 4; ++j) {
        const int c = wave + j * 4;
        gll16(&Ab[(long)(c * 8 + srow) * K + k0 + 64 + cg * 8], &lA[nxt][c * 512]);
        gll16(&Bb[(long)(c * 8 + srow) * K + k0 + 64 + cg * 8], &lB[nxt][c * 512]);
      }
    }
#pragma unroll
    for (int ks = 0; ks < 2; ++ks) {
      bf16x8 af[4], bfr[4];
#pragma unroll
      for (int mi = 0; mi < 4; mi++) {
        const int row = wm * 64 + mi * 16 + l16;
        af[mi] = *(const bf16x8*)&lA[cur][row * 64 +
                                          (((ks * 4 + quad) ^ (l16 & 7)) * 8)];
      }
#pragma unroll
      for (int ni = 0; ni < 4; ni++) {
        const int row = wn * 64 + ni * 16 + l16;
        bfr[ni] = *(const bf16x8*)&lB[cur][row * 64 +
                                           (((ks * 4 + quad) ^ (l16 & 7)) * 8)];
      }
#pragma unroll
      for (int mi = 0; mi < 4; mi++)
#pragma unroll
        for (int ni = 0; ni < 4; ni++)
          acc[mi][ni] = MFMA16(af[mi], bfr[ni], acc[mi][ni]);
    }
    cur ^= 1;
  }

#pragma unroll
  for (int mi = 0; mi < 4; mi++) {
#pragma unroll
    for (int ni = 0; ni < 4; ni++) {
#pragma unroll
      for (int r = 0; r < 4; r++) {
        const long row = m0 + wm * 64 + mi * 16 + quad * 4 + r;
        const long col = n0 + wn * 64 + ni * 16 + l16;
        const long idx = row * N + col;
        float v = acc[mi][ni][r];
        if (EPI == 0) {
          ((__hip_bfloat16*)Cv)[idx] = __float2bfloat16(v);
        } else if (EPI == 1) {
          ((float*)Cv)[idx] = v + res[idx];
        } else if (EPI == 2) {
          v += bias[col];
          ((__hip_bfloat16*)Cv)[idx] = __float2bfloat16(fmaxf(v, 0.f));
        } else if (EPI == 3) {
          float* Cf = (float*)Cv;
          Cf[idx] = Cf[idx] + v;
        }
      }
    }
  }
}

// ---------------------------------------------------------------------------
// 128x64-tile variant for N=1024 GEMMs (wo, ffn2): BK=64 swizzled (round 6).
// ---------------------------------------------------------------------------
template <int EPI>
__global__ __launch_bounds__(256) void gemm64_bt_kernel(
    const __hip_bfloat16* __restrict__ A, const __hip_bfloat16* __restrict__ Bt,
    void* __restrict__ Cv, const float* __restrict__ bias,
    const float* __restrict__ res, int M, int N, int K) {
  __shared__ __align__(16) __hip_bfloat16 lA[2][128 * 64];
  __shared__ __align__(16) __hip_bfloat16 lB[2][64 * 64];
  const int tid = threadIdx.x;
  const int wave = tid >> 6, lane = tid & 63;
  const int quad = lane >> 4, l16 = lane & 15;
  const int wm = wave >> 1, wn = wave & 1;

  const int gx = gridDim.x;
  const int nwg = gx * gridDim.y;
  int bid = blockIdx.y * gx + blockIdx.x;
  bid = (bid & 7) * (nwg >> 3) + (bid >> 3);
  const long m0 = (long)(bid / gx) * 128;
  const long n0 = (long)(bid % gx) * 64;

  const int srow = lane >> 3;
  const int cg = (lane & 7) ^ srow;

  floatx4 acc[4][2];
#pragma unroll
  for (int i = 0; i < 4; i++)
#pragma unroll
    for (int j = 0; j < 2; j++) acc[i][j] = (floatx4){0.f, 0.f, 0.f, 0.f};

  const __hip_bfloat16* Ab = A + m0 * K;
  const __hip_bfloat16* Bb = Bt + n0 * K;

#pragma unroll
  for (int j = 0; j < 4; ++j) {
    const int c = wave + j * 4;
    gll16(&Ab[(long)(c * 8 + srow) * K + cg * 8], &lA[0][c * 512]);
  }
#pragma unroll
  for (int j = 0; j < 2; ++j) {
    const int c = wave + j * 4;
    gll16(&Bb[(long)(c * 8 + srow) * K + cg * 8], &lB[0][c * 512]);
  }

  int cur = 0;
  for (int k0 = 0; k0 < K; k0 += 64) {
    __syncthreads();
    if (k0 + 64 < K) {
      const int nxt = cur ^ 1;
#pragma unroll
      for (int j = 0; j < 4; ++j) {
        const int c = wave + j * 4;
        gll16(&Ab[(long)(c * 8 + srow) * K + k0 + 64 + cg * 8], &lA[nxt][c * 512]);
      }
#pragma unroll
      for (int j = 0; j < 2; ++j) {
        const int c = wave + j * 4;
        gll16(&Bb[(long)(c * 8 + srow) * K + k0 + 64 + cg * 8], &lB[nxt][c * 512]);
      }
    }
#pragma unroll
    for (int ks = 0; ks < 2; ++ks) {
      bf16x8 af[4], bfr[2];
#pragma unroll
      for (int mi = 0; mi < 4; mi++) {
        const int row = wm * 64 + mi * 16 + l16;
        af[mi] = *(const bf16x8*)&lA[cur][row * 64 +
                                          (((ks * 4 + quad) ^ (l16 & 7)) * 8)];
      }
#pragma unroll
      for (int ni = 0; ni < 2; ni++) {
        const int row = wn * 32 + ni * 16 + l16;
        bfr[ni] = *(const bf16x8*)&lB[cur][row * 64 +
                                           (((ks * 4 + quad) ^ (l16 & 7)) * 8)];
      }
#pragma unroll
      for (int mi = 0; mi < 4; mi++)
#pragma unroll
        for (int ni = 0; ni < 2; ni++)
          acc[mi][ni] = MFMA16(af[mi], bfr[ni], acc[mi][ni]);
    }
    cur ^= 1;
  }

#pragma unroll
  for (int mi = 0; mi < 4; mi++) {
#pragma unroll
    for (int ni = 0; ni < 2; ni++) {
#pragma unroll
      for (int r = 0; r < 4; r++) {
        const long row = m0 + wm * 64 + mi * 16 + quad * 4 + r;
        const long col = n0 + wn * 32 + ni * 16 + l16;
        const long idx = row * N + col;
        float v = acc[mi][ni][r];
        if (EPI == 1) {
          ((float*)Cv)[idx] = v + res[idx];
        } else if (EPI == 3) {
          float* Cf = (float*)Cv;
          Cf[idx] = Cf[idx] + v;
        }
      }
    }
  }
}

// ---------------------------------------------------------------------------
// Flash attention. r9 proved chain-bound (FETCH 69.7->12.3 MB, time flat).
// Round 10 (T15 one-stage PV delay): per iteration run PV(t-1) alongside
// QK(t) — PV is independent of tile t, so the chain shortens from
// QK->softmax->PV to max(PV_prev,QK)->softmax (m214: +7-11%).
//  * V triple-buffered: DMA(t+1) writes (t+1)%3, PV reads (t-1)%3 — always
//    distinct; barrier at t drains DMA(t) before QK(t) reads K.
//  * lP single: PV(t-1) reads lP before softmax(t) overwrites (same-wave DS
//    order + aliasing preserve this).
//  * rs/tms carried one iteration; fixup(t-1) before softmax(t) uses mrow —
//    identical online-softmax semantics.
// LDS 16(K)+24(V)+8(P) = 48 KB -> 3 blocks/CU (was 4; r8 showed tolerance).
// ---------------------------------------------------------------------------
__global__ __launch_bounds__(256) void attn_kernel(
    const __hip_bfloat16* __restrict__ qkv, const __hip_bfloat16* __restrict__ vt,
    const float* __restrict__ addm, const int* __restrict__ flags,
    __hip_bfloat16* __restrict__ ctx) {
  __shared__ __align__(16) __hip_bfloat16 lK[2][64 * 64];
  __shared__ __align__(16) __hip_bfloat16 lV[3][64 * 64];
  __shared__ __align__(16) __hip_bfloat16 lP[4][16 * 64];  // wave-private P^T
  const int tid = threadIdx.x, wave = tid >> 6, lane = tid & 63;
  const int quad = lane >> 4, l16 = lane & 15;
  // XCD-chunked swizzle over the flat 1024-block grid (r9: FETCH -82%)
  const int nwg = gridDim.x * gridDim.y;
  int bid0 = blockIdx.y * gridDim.x + blockIdx.x;
  bid0 = (bid0 & 7) * (nwg >> 3) + (bid0 >> 3);
  const int bh = bid0 >> 5, b = bh >> 4, h = bh & 15;
  const int q0 = (bid0 & 31) * 64 + wave * 16;
  const float cs = 0.18033688011112042f;   // log2(e)/sqrt(64)
  const float inv_cs = 5.545177444479562f; // sqrt(64)/log2(e)

  const __hip_bfloat16* kb = qkv + (long)b * 2048 * 3072 + 1024 + h * 64;
  const __hip_bfloat16* vb = vt + (long)bh * 64 * 2048;
  const float* am = addm + b * 2048;

  int fm = 1;
#pragma unroll
  for (int i = 0; i < 8; ++i) fm &= flags[b * 8 + i];
  const bool fast = (fm != 0);

  const long qoff = ((long)b * 2048 + q0 + l16) * 3072 + h * 64;
  const bf16x8 bq0 = *(const bf16x8*)&qkv[qoff + quad * 8];
  const bf16x8 bq1 = *(const bf16x8*)&qkv[qoff + 32 + quad * 8];

  const int srow = lane >> 3;
  const int cslot = lane & 7;
  const int cg = cslot ^ srow;
  const int rbase = wave * 16 + srow;

  // P-buffer addresses (bytes within this wave's 2 KB region)
  char* const pbase = (char*)&lP[wave][0];
  const int prow = l16 * 128;
  const int pswz = l16 & 7;

  floatx4 o[4];
#pragma unroll
  for (int mi = 0; mi < 4; mi++) o[mi] = (floatx4){0.f, 0.f, 0.f, 0.f};
  float mrow = 10.0f, lrow = 0.f;  // mrow in log2 units (score*cs domain)
  float rs_prev = 0.f, tms_prev = -3.0e38f;

  // prologue: stage tile 0 into K0 / V0
#pragma unroll
  for (int j = 0; j < 2; ++j) {
    const int rloc = rbase + j * 8;
    gll16(kb + (long)rloc * 3072 + cg * 8, &lK[0][(wave * 16 + j * 8) * 64]);
    gll16(vb + (long)rloc * 2048 + cg * 8, &lV[0][(wave * 16 + j * 8) * 64]);
  }

  int kcur = 0;     // t & 1
  int vN = 1;       // (t+1) % 3
  int vP = 2;       // (t-1) % 3  (unused at t=0)
  for (int t = 0; t <= 32; ++t) {
    __syncthreads();  // drains DMA(t) issued last iteration
    if (t + 1 < 32) {
      const int knxt = kcur ^ 1;
#pragma unroll
      for (int j = 0; j < 2; ++j) {
        const int rloc = rbase + j * 8;
        gll16(kb + (long)((t + 1) * 64 + rloc) * 3072 + cg * 8,
              &lK[knxt][(wave * 16 + j * 8) * 64]);
        gll16(vb + (long)rloc * 2048 + (t + 1) * 64 + cg * 8,
              &lV[vN][(wave * 16 + j * 8) * 64]);
      }
    }

    // ---- PV(t-1): independent of tile t — overlaps QK(t) below ----
    if (t >= 1) {
      const __hip_bfloat16* lVp = lV[vP];
#pragma unroll
      for (int ss = 0; ss < 2; ++ss) {
        const bf16x8 bp = *(const bf16x8*)(pbase + prow +
                                           ((((ss << 2) + quad) ^ pswz) << 4));
        __builtin_amdgcn_s_setprio(1);
#pragma unroll
        for (int mi = 0; mi < 4; ++mi) {
          const bf16x8 av = *(const bf16x8*)&lVp[(mi * 16 + l16) * 64 +
                                                 ((ss * 4 + quad) ^ (l16 & 7)) * 8];
          o[mi] = MFMA16(av, bp, o[mi]);
        }
        __builtin_amdgcn_s_setprio(0);
      }
      lrow += rs_prev;
      if (__any(tms_prev > mrow + 8.f)) {
        const float mnew = fmaxf(mrow, tms_prev);
        const float alpha = __builtin_amdgcn_exp2f(mrow - mnew);
        mrow = mnew;
        lrow *= alpha;
#pragma unroll
        for (int mi = 0; mi < 4; mi++) o[mi] *= alpha;
      }
    }

    // ---- QK(t) + softmax(t) -> lP, rs/tms for next iteration ----
    if (t < 32) {
      const __hip_bfloat16* lKc = lK[kcur];
      floatx4 c[4];
      __builtin_amdgcn_s_setprio(1);
#pragma unroll
      for (int g = 0; g < 4; ++g) {
        const bf16x8 a0 =
            *(const bf16x8*)&lKc[(g * 16 + l16) * 64 + ((quad) ^ (l16 & 7)) * 8];
        const bf16x8 a1 =
            *(const bf16x8*)&lKc[(g * 16 + l16) * 64 + ((4 + quad) ^ (l16 & 7)) * 8];
        floatx4 cc = {0.f, 0.f, 0.f, 0.f};
        cc = MFMA16(a0, bq0, cc);
        cc = MFMA16(a1, bq1, cc);
        c[g] = cc;
      }
      __builtin_amdgcn_s_setprio(0);

      if (!fast) {
#pragma unroll
        for (int g = 0; g < 4; ++g) {
          const float4 a4 = *(const float4*)&am[t * 64 + g * 16 + quad * 4];
          c[g][0] = fmaf(a4.x, inv_cs, c[g][0]);
          c[g][1] = fmaf(a4.y, inv_cs, c[g][1]);
          c[g][2] = fmaf(a4.z, inv_cs, c[g][2]);
          c[g][3] = fmaf(a4.w, inv_cs, c[g][3]);
        }
      }

      const float mneg = -mrow;
      float p[4][4];
#pragma unroll
      for (int g = 0; g < 4; ++g)
#pragma unroll
        for (int r = 0; r < 4; ++r)
          p[g][r] = __builtin_amdgcn_exp2f(fmaf(c[g][r], cs, mneg));

      // pack P into the wave-private LDS transpose buffer (read next iter)
#pragma unroll
      for (int g = 0; g < 4; ++g) {
        uint2 w2;
        w2.x = cvtpk(p[g][0], p[g][1]);
        w2.y = cvtpk(p[g][2], p[g][3]);
        const int slot16 = (g * 2 + (quad >> 1)) ^ pswz;
        *(uint2*)(pbase + prow + (slot16 << 4) + ((quad & 1) << 3)) = w2;
      }

      const float m0 = fmaxf(fmaxf(c[0][0], c[0][1]), c[0][2]);
      const float m1 = fmaxf(fmaxf(c[0][3], c[1][0]), c[1][1]);
      const float m2 = fmaxf(fmaxf(c[1][2], c[1][3]), c[2][0]);
      const float m3 = fmaxf(fmaxf(c[2][1], c[2][2]), c[2][3]);
      const float m4 = fmaxf(fmaxf(c[3][0], c[3][1]), c[3][2]);
      float tm = fmaxf(fmaxf(fmaxf(m0, m1), fmaxf(m2, m3)), fmaxf(m4, c[3][3]));
      tm = fmaxf(tm, __shfl_xor(tm, 16));
      tm = fmaxf(tm, __shfl_xor(tm, 32));
      tms_prev = tm * cs;

      const float s0 = (p[0][0] + p[0][1]) + (p[0][2] + p[0][3]);
      const float s1 = (p[1][0] + p[1][1]) + (p[1][2] + p[1][3]);
      const float s2 = (p[2][0] + p[2][1]) + (p[2][2] + p[2][3]);
      const float s3 = (p[3][0] + p[3][1]) + (p[3][2] + p[3][3]);
      float rs = (s0 + s1) + (s2 + s3);
      rs += __shfl_xor(rs, 16);
      rs += __shfl_xor(rs, 32);
      rs_prev = rs;
    }

    kcur ^= 1;
    vN = (vN == 2) ? 0 : vN + 1;
    vP = (vP == 2) ? 0 : vP + 1;
  }

  const float inv_l = 1.f / lrow;
  const long cb = ((long)b * 2048 + q0 + l16) * 1024 + h * 64;
#pragma unroll
  for (int mi = 0; mi < 4; mi++) {
    uint2 st;
    st.x = cvtpk(o[mi][0] * inv_l, o[mi][1] * inv_l);
    st.y = cvtpk(o[mi][2] * inv_l, o[mi][3] * inv_l);
    *(uint2*)&ctx[cb + mi * 16 + quad * 4] = st;
  }
}

// ---------------------------------------------------------------------------
// ws plan (peak 32 MiB) + d_out (16 MiB) as scratch:
//  A: ln_qkvtrans (1792 blocks): ln1 x->xn(d_out[0,8)) + wqkvT ws[24,30);
//     qkv-gemm (BK=32) -> qkv ws[0,24)
//  B: prep: vtrans -> vtb ws[24,32); woT -> d_out[8,10); mask -> addm+flags;
//     attn (T15 pipelined, XCD-swizzled) -> ctxb(d_out[0,8))
//  C: wo-gemm64(ctxb,woT)+x -> x1 f32 ws[0,16)  (EPI1)
//  D: ln2_wtrans (2048 blocks): ln2 x1->xn2(d_out[0,8)) + wtrans(c=0)
//  E: ffn1-k64(c=0) -> hc ws[16,32); ffn2-gemm64(c=0): x1 += (EPI3);
//     wtrans(c=1); ffn1-k64(c=1); ffn2-gemm64(c=1)
//  F: bias_add: d_out = x1 + b2
//  12 launches.
// ---------------------------------------------------------------------------
extern "C" void kernel_launch(void* const* d_in, const int* in_sizes, int n_in,
                              void* d_out, int out_size, void* d_ws, size_t ws_size,
                              hipStream_t stream) {
  const float* x = (const float*)d_in[0];
  const int* mask = (const int*)d_in[1];
  const float* wq = (const float*)d_in[2];
  const float* wk = (const float*)d_in[3];
  const float* wv = (const float*)d_in[4];
  const float* wo = (const float*)d_in[5];
  const float* w1 = (const float*)d_in[6];
  const float* b1 = (const float*)d_in[7];
  const float* w2 = (const float*)d_in[8];
  const float* b2 = (const float*)d_in[9];
  const float* alpha1 = (const float*)d_in[10];
  const float* bias1 = (const float*)d_in[11];
  const float* alpha2 = (const float*)d_in[12];
  const float* bias2 = (const float*)d_in[13];

  char* ws = (char*)d_ws;
  char* dob = (char*)d_out;
  const size_t MiB = 1048576;
  __hip_bfloat16* qkv   = (__hip_bfloat16*)(ws + 0);          // [0,24)
  __hip_bfloat16* wqkvT = (__hip_bfloat16*)(ws + 24 * MiB);   // [24,30)
  __hip_bfloat16* vtb   = (__hip_bfloat16*)(ws + 24 * MiB);   // [24,32)
  float*          x1    = (float*)(ws + 0);                   // [0,16) f32
  __hip_bfloat16* hc    = (__hip_bfloat16*)(ws + 16 * MiB);   // [16,32)
  __hip_bfloat16* xn    = (__hip_bfloat16*)d_out;             // d_out[0,8) bf16
  __hip_bfloat16* ctxb  = (__hip_bfloat16*)d_out;
  __hip_bfloat16* xn2   = (__hip_bfloat16*)d_out;
  __hip_bfloat16* woT   = (__hip_bfloat16*)(dob + 8 * MiB);   // d_out[8,10)
  __hip_bfloat16* w1Th  = (__hip_bfloat16*)(dob + 8 * MiB);   // d_out[8,12)
  __hip_bfloat16* w2Th  = (__hip_bfloat16*)(dob + 12 * MiB);  // d_out[12,16)
  float*          addm  = (float*)(dob + 12 * MiB);           // d_out[12M,+16K)
  int*            flags = (int*)(dob + 12 * MiB + 16 * 1024); // 64 B after addm

  const dim3 b256(256);
  // Stage A
  ln_qkvtrans_kernel<<<1792, b256, 0, stream>>>(x, xn, alpha1, bias1,
                                                wq, wk, wv, wqkvT);
  gemm_bt_kernel<0><<<dim3(24, 32), b256, 0, stream>>>(xn, wqkvT, qkv, nullptr,
                                                       nullptr, 4096, 3072, 1024);
  // Stage B
  prep_kernel<<<1296, b256, 0, stream>>>(qkv, vtb, wo, woT, mask, addm, flags);
  attn_kernel<<<dim3(32, 32), b256, 0, stream>>>(qkv, vtb, addm, flags, ctxb);
  // Stage C
  gemm64_bt_kernel<1><<<dim3(16, 32), b256, 0, stream>>>(ctxb, woT, x1, nullptr, x,
                                                         4096, 1024, 1024);
  // Stage D (merged ln2 + wtrans c=0)
  ln2_wtrans_kernel<<<2048, b256, 0, stream>>>(x1, xn2, alpha2, bias2,
                                               w1, w2, w1Th, w2Th);
  // Stage E
  gemm_bt_k64_kernel<2><<<dim3(16, 32), b256, 0, stream>>>(xn2, w1Th, hc,
                                                           b1, nullptr,
                                                           4096, 2048, 1024);
  gemm64_bt_kernel<3><<<dim3(16, 32), b256, 0, stream>>>(hc, w2Th, x1, nullptr,
                                                         nullptr, 4096, 1024, 2048);
  wtrans_kernel<<<1024, b256, 0, stream>>>(w1 + 2048,
                                           w2 + (size_t)2048 * 1024,
                                           w1Th, w2Th);
  gemm_bt_k64_kernel<2><<<dim3(16, 32), b256, 0, stream>>>(xn2, w1Th, hc,
                                                           b1 + 2048, nullptr,
                                                           4096, 2048, 1024);
  gemm64_bt_kernel<3><<<dim3(16, 32), b256, 0, stream>>>(hc, w2Th, x1, nullptr,
                                                         nullptr, 4096, 1024, 2048);
  // Stage F
  bias_add_kernel<<<4096, b256, 0, stream>>>(x1, b2, (float*)d_out);
}

// Round 11
// 380.682 us; speedup vs baseline: 1.0546x; 1.0546x over previous
//
#include <hip/hip_runtime.h>
#include <hip/hip_bf16.h>

typedef __attribute__((ext_vector_type(8))) short bf16x8;
typedef __attribute__((ext_vector_type(4))) short short4v;
typedef __attribute__((ext_vector_type(4))) float floatx4;

#define MFMA16(A, B, C) __builtin_amdgcn_mfma_f32_16x16x32_bf16((A), (B), (C), 0, 0, 0)

__device__ inline short bf16bits(float f) {
  __hip_bfloat16 h = __float2bfloat16(f);
  return *reinterpret_cast<short*>(&h);
}
// HW packed f32->bf16 (RNE). No builtin on gfx950 (m240) -> inline asm.
__device__ inline unsigned cvtpk(float lo, float hi) {
  unsigned r;
  asm("v_cvt_pk_bf16_f32 %0, %1, %2" : "=v"(r) : "v"(lo), "v"(hi));
  return r;
}
typedef __attribute__((address_space(3))) char lds_char;
typedef __attribute__((address_space(1))) const char glob_char;
__device__ inline void gll16(const void* g, void* l) {
  __builtin_amdgcn_global_load_lds((glob_char*)g, (lds_char*)l, 16, 0, 0);
}

// ---------------------------------------------------------------------------
// Merged ln1 + wqkv transpose; LN wave-per-row (round 10 — kept, ~-2.5 us).
// Grid 1792 (1024 LN + 768 transpose).
// ---------------------------------------------------------------------------
__global__ __launch_bounds__(256) void ln_qkvtrans_kernel(
    const float* __restrict__ x, __hip_bfloat16* __restrict__ y,
    const float* __restrict__ alpha_p, const float* __restrict__ bias_p,
    const float* __restrict__ wq, const float* __restrict__ wk,
    const float* __restrict__ wv, __hip_bfloat16* __restrict__ wqkvT) {
  __shared__ __align__(16) __hip_bfloat16 tile[64][72];
  const int bid = blockIdx.x;
  const int t = threadIdx.x;
  if (bid < 1024) {
    const int wvv = t >> 6, lane = t & 63;
    const long row = (long)bid * 4 + wvv;
    const float* xr = x + row * 1024;
    float4 v4[4];
#pragma unroll
    for (int i = 0; i < 4; i++) v4[i] = *(const float4*)&xr[lane * 4 + i * 256];
    float sum = 0.f, sq = 0.f;
#pragma unroll
    for (int i = 0; i < 4; i++) {
      sum += (v4[i].x + v4[i].y) + (v4[i].z + v4[i].w);
      sq += (v4[i].x * v4[i].x + v4[i].y * v4[i].y) +
            (v4[i].z * v4[i].z + v4[i].w * v4[i].w);
    }
#pragma unroll
    for (int off = 32; off; off >>= 1) {
      sum += __shfl_xor(sum, off);
      sq += __shfl_xor(sq, off);
    }
    const float mean = sum * (1.f / 1024.f);
    float var = (sq - 1024.f * mean * mean) * (1.f / 1023.f);
    var = fmaxf(var, 0.f);
    const float denom = sqrtf(var) + 1e-5f;
    const float sc = alpha_p[0] / denom;
    const float beta = bias_p[0];
    __hip_bfloat16* yr = y + row * 1024;
#pragma unroll
    for (int i = 0; i < 4; i++) {
      uint2 st;
      st.x = cvtpk((v4[i].x - mean) * sc + beta, (v4[i].y - mean) * sc + beta);
      st.y = cvtpk((v4[i].z - mean) * sc + beta, (v4[i].w - mean) * sc + beta);
      *(uint2*)&yr[lane * 4 + i * 256] = st;
    }
  } else {
    const int tt = bid - 1024;
    const int which = tt >> 8;
    const float* src = which == 0 ? wq : (which == 1 ? wk : wv);
    __hip_bfloat16* dst = wqkvT + (size_t)which * 1024 * 1024;
    const long r0 = (long)((tt >> 4) & 15) * 64, c0 = (long)(tt & 15) * 64;
    for (int i = t; i < 1024; i += 256) {
      int r = i >> 4, c4 = (i & 15) * 4;
      float4 f = *(const float4*)&src[(r0 + r) * 1024 + c0 + c4];
      short4v s;
      s[0] = bf16bits(f.x); s[1] = bf16bits(f.y);
      s[2] = bf16bits(f.z); s[3] = bf16bits(f.w);
      *(short4v*)&tile[r][c4] = s;
    }
    __syncthreads();
    for (int i = t; i < 512; i += 256) {
      int c = i >> 3, r8 = (i & 7) * 8;
      bf16x8 sv;
#pragma unroll
      for (int j = 0; j < 8; j++) sv[j] = *reinterpret_cast<const short*>(&tile[r8 + j][c]);
      *(bf16x8*)&dst[(c0 + c) * 1024 + r0 + r8] = sv;
    }
  }
}

// ---------------------------------------------------------------------------
// Merged stage-B prep kernel (round 6).
// ---------------------------------------------------------------------------
__global__ __launch_bounds__(256) void prep_kernel(
    const __hip_bfloat16* __restrict__ qkv, __hip_bfloat16* __restrict__ vt,
    const float* __restrict__ wo, __hip_bfloat16* __restrict__ woT,
    const int* __restrict__ mask, float* __restrict__ addm,
    int* __restrict__ flags) {
  __shared__ __align__(16) __hip_bfloat16 tile[64][72];
  __shared__ int ok[4];
  const int bid = blockIdx.x;
  if (bid < 1024) {
    const int bh = bid >> 5, b = bh >> 4, h = bh & 15;
    const long s0 = (long)(bid & 31) * 64;
    const __hip_bfloat16* src = qkv + ((long)b * 2048 + s0) * 3072 + 2048 + h * 64;
    for (int i = threadIdx.x; i < 512; i += 256) {
      int s = i >> 3, d8 = (i & 7) * 8;
      *(uint4*)&tile[s][d8] = *(const uint4*)&src[(long)s * 3072 + d8];
    }
    __syncthreads();
    __hip_bfloat16* dstb = vt + (long)bh * 64 * 2048 + s0;
    for (int i = threadIdx.x; i < 512; i += 256) {
      int d = i >> 3, s8 = (i & 7) * 8;
      bf16x8 sv;
#pragma unroll
      for (int j = 0; j < 8; j++) sv[j] = *reinterpret_cast<const short*>(&tile[s8 + j][d]);
      *(bf16x8*)&dstb[(long)d * 2048 + s8] = sv;
    }
  } else if (bid < 1280) {
    const int t = bid - 1024;
    const long r0 = (long)(t >> 4) * 64, c0 = (long)(t & 15) * 64;
    for (int i = threadIdx.x; i < 1024; i += 256) {
      int r = i >> 4, c4 = (i & 15) * 4;
      float4 f = *(const float4*)&wo[(r0 + r) * 1024 + c0 + c4];
      short4v s;
      s[0] = bf16bits(f.x); s[1] = bf16bits(f.y);
      s[2] = bf16bits(f.z); s[3] = bf16bits(f.w);
      *(short4v*)&tile[r][c4] = s;
    }
    __syncthreads();
    for (int i = threadIdx.x; i < 512; i += 256) {
      int c = i >> 3, r8 = (i & 7) * 8;
      bf16x8 sv;
#pragma unroll
      for (int j = 0; j < 8; j++) sv[j] = *reinterpret_cast<const short*>(&tile[r8 + j][c]);
      *(bf16x8*)&woT[(c0 + c) * 1024 + r0 + r8] = sv;
    }
  } else {
    const int i = (bid - 1280) * 256 + threadIdx.x;
    const int mv = mask[i];
    addm[i] = mv ? 0.f : -1e30f;
    const unsigned long long bal = __ballot(mv != 0);
    if ((threadIdx.x & 63) == 0) ok[threadIdx.x >> 6] = (bal == ~0ull) ? 1 : 0;
    __syncthreads();
    if (threadIdx.x == 0) flags[bid - 1280] = ok[0] & ok[1] & ok[2] & ok[3];
  }
}

// ---------------------------------------------------------------------------
// Merged ln2 + wtrans(c=0), LN wave-per-row (round 10 — kept). Grid 2048.
// ---------------------------------------------------------------------------
__global__ __launch_bounds__(256) void ln2_wtrans_kernel(
    const float* __restrict__ x1, __hip_bfloat16* __restrict__ xn2,
    const float* __restrict__ alpha_p, const float* __restrict__ bias_p,
    const float* __restrict__ w1c, const float* __restrict__ w2c,
    __hip_bfloat16* __restrict__ w1Th, __hip_bfloat16* __restrict__ w2Th) {
  __shared__ __align__(16) __hip_bfloat16 tile[64][72];
  const int bid = blockIdx.x;
  const int t = threadIdx.x;
  if (bid < 1024) {
    const int wvv = t >> 6, lane = t & 63;
    const long row = (long)bid * 4 + wvv;
    const float* xr = x1 + row * 1024;
    float4 v4[4];
#pragma unroll
    for (int i = 0; i < 4; i++) v4[i] = *(const float4*)&xr[lane * 4 + i * 256];
    float sum = 0.f, sq = 0.f;
#pragma unroll
    for (int i = 0; i < 4; i++) {
      sum += (v4[i].x + v4[i].y) + (v4[i].z + v4[i].w);
      sq += (v4[i].x * v4[i].x + v4[i].y * v4[i].y) +
            (v4[i].z * v4[i].z + v4[i].w * v4[i].w);
    }
#pragma unroll
    for (int off = 32; off; off >>= 1) {
      sum += __shfl_xor(sum, off);
      sq += __shfl_xor(sq, off);
    }
    const float mean = sum * (1.f / 1024.f);
    float var = (sq - 1024.f * mean * mean) * (1.f / 1023.f);
    var = fmaxf(var, 0.f);
    const float denom = sqrtf(var) + 1e-5f;
    const float sc = alpha_p[0] / denom;
    const float beta = bias_p[0];
    __hip_bfloat16* yr = xn2 + row * 1024;
#pragma unroll
    for (int i = 0; i < 4; i++) {
      uint2 st;
      st.x = cvtpk((v4[i].x - mean) * sc + beta, (v4[i].y - mean) * sc + beta);
      st.y = cvtpk((v4[i].z - mean) * sc + beta, (v4[i].w - mean) * sc + beta);
      *(uint2*)&yr[lane * 4 + i * 256] = st;
    }
  } else {
    const int wb = bid - 1024;
    const float* src;
    __hip_bfloat16* dst;
    int R, ldS;
    long r0, c0;
    if (wb < 512) {
      src = w1c; dst = w1Th; R = 1024; ldS = 4096;
      r0 = (long)(wb >> 5) * 64; c0 = (long)(wb & 31) * 64;
    } else {
      const int t2 = wb - 512;
      src = w2c; dst = w2Th; R = 2048; ldS = 1024;
      r0 = (long)(t2 >> 4) * 64; c0 = (long)(t2 & 15) * 64;
    }
    for (int i = t; i < 1024; i += 256) {
      int r = i >> 4, c4 = (i & 15) * 4;
      float4 f = *(const float4*)&src[(r0 + r) * ldS + c0 + c4];
      short4v s;
      s[0] = bf16bits(f.x); s[1] = bf16bits(f.y);
      s[2] = bf16bits(f.z); s[3] = bf16bits(f.w);
      *(short4v*)&tile[r][c4] = s;
    }
    __syncthreads();
    for (int i = t; i < 512; i += 256) {
      int c = i >> 3, r8 = (i & 7) * 8;
      bf16x8 sv;
#pragma unroll
      for (int j = 0; j < 8; j++) sv[j] = *reinterpret_cast<const short*>(&tile[r8 + j][c]);
      *(bf16x8*)&dst[(c0 + c) * R + r0 + r8] = sv;
    }
  }
}

// ---------------------------------------------------------------------------
// Merged per-half FFN weight transpose (round 6) — used for c=1.
// ---------------------------------------------------------------------------
__global__ __launch_bounds__(256) void wtrans_kernel(
    const float* __restrict__ w1c, const float* __restrict__ w2c,
    __hip_bfloat16* __restrict__ w1Th, __hip_bfloat16* __restrict__ w2Th) {
  __shared__ __align__(16) __hip_bfloat16 tile[64][72];
  const int bid = blockIdx.x;
  const float* src;
  __hip_bfloat16* dst;
  int R, ldS;
  long r0, c0;
  if (bid < 512) {
    src = w1c; dst = w1Th; R = 1024; ldS = 4096;
    r0 = (long)(bid >> 5) * 64; c0 = (long)(bid & 31) * 64;
  } else {
    const int t = bid - 512;
    src = w2c; dst = w2Th; R = 2048; ldS = 1024;
    r0 = (long)(t >> 4) * 64; c0 = (long)(t & 15) * 64;
  }
  for (int i = threadIdx.x; i < 1024; i += 256) {
    int r = i >> 4, c4 = (i & 15) * 4;
    float4 f = *(const float4*)&src[(r0 + r) * ldS + c0 + c4];
    short4v s;
    s[0] = bf16bits(f.x); s[1] = bf16bits(f.y);
    s[2] = bf16bits(f.z); s[3] = bf16bits(f.w);
    *(short4v*)&tile[r][c4] = s;
  }
  __syncthreads();
  for (int i = threadIdx.x; i < 512; i += 256) {
    int c = i >> 3, r8 = (i & 7) * 8;
    bf16x8 sv;
#pragma unroll
    for (int j = 0; j < 8; j++) sv[j] = *reinterpret_cast<const short*>(&tile[r8 + j][c]);
    *(bf16x8*)&dst[(c0 + c) * R + r0 + r8] = sv;
  }
}

// ---------------------------------------------------------------------------
// d_out = x1 + b2 (broadcast over rows), fp32
// ---------------------------------------------------------------------------
__global__ __launch_bounds__(256) void bias_add_kernel(
    const float* __restrict__ x1, const float* __restrict__ b2,
    float* __restrict__ out) {
  const int i = (blockIdx.x * 256 + threadIdx.x) * 4;
  float4 v = *(const float4*)&x1[i];
  const float4 bb = *(const float4*)&b2[i & 1023];
  v.x += bb.x; v.y += bb.y; v.z += bb.z; v.w += bb.w;
  *(float4*)&out[i] = v;
}

// ---------------------------------------------------------------------------
// bf16 GEMM, B pre-transposed: 128x128 tile, BK=32, dbuf + XCD swizzle.
// Used for the qkv GEMM (3 blocks/CU).
// ---------------------------------------------------------------------------
template <int EPI>
__global__ __launch_bounds__(256) void gemm_bt_kernel(
    const __hip_bfloat16* __restrict__ A, const __hip_bfloat16* __restrict__ Bt,
    void* __restrict__ Cv, const float* __restrict__ bias,
    const float* __restrict__ res, int M, int N, int K) {
  __shared__ __align__(16) __hip_bfloat16 lA[2][128 * 32];
  __shared__ __align__(16) __hip_bfloat16 lB[2][128 * 32];
  const int tid = threadIdx.x;
  const int wave = tid >> 6, lane = tid & 63;
  const int quad = lane >> 4, l16 = lane & 15;
  const int wm = wave >> 1, wn = wave & 1;

  const int gx = gridDim.x;
  const int nwg = gx * gridDim.y;
  int bid = blockIdx.y * gx + blockIdx.x;
  bid = (bid & 7) * (nwg >> 3) + (bid >> 3);
  const long m0 = (long)(bid / gx) * 128;
  const long n0 = (long)(bid % gx) * 128;

  const int rA0 = tid >> 2, cA0 = (tid & 3) * 8;
  const int rA1 = (tid + 256) >> 2, cA1 = ((tid + 256) & 3) * 8;

  floatx4 acc[4][4];
#pragma unroll
  for (int i = 0; i < 4; i++)
#pragma unroll
    for (int j = 0; j < 4; j++) acc[i][j] = (floatx4){0.f, 0.f, 0.f, 0.f};

  const __hip_bfloat16* Ab = A + m0 * K;
  const __hip_bfloat16* Bb = Bt + n0 * K;

  gll16(&Ab[(long)rA0 * K + cA0], &lA[0][wave * 512]);
  gll16(&Ab[(long)rA1 * K + cA1], &lA[0][2048 + wave * 512]);
  gll16(&Bb[(long)rA0 * K + cA0], &lB[0][wave * 512]);
  gll16(&Bb[(long)rA1 * K + cA1], &lB[0][2048 + wave * 512]);

  int cur = 0;
  for (int k0 = 0; k0 < K; k0 += 32) {
    __syncthreads();
    if (k0 + 32 < K) {
      const int nxt = cur ^ 1;
      gll16(&Ab[(long)rA0 * K + k0 + 32 + cA0], &lA[nxt][wave * 512]);
      gll16(&Ab[(long)rA1 * K + k0 + 32 + cA1], &lA[nxt][2048 + wave * 512]);
      gll16(&Bb[(long)rA0 * K + k0 + 32 + cA0], &lB[nxt][wave * 512]);
      gll16(&Bb[(long)rA1 * K + k0 + 32 + cA1], &lB[nxt][2048 + wave * 512]);
    }
    bf16x8 af[4], bfr[4];
#pragma unroll
    for (int mi = 0; mi < 4; mi++)
      af[mi] = *(const bf16x8*)&lA[cur][(wm * 64 + mi * 16 + l16) * 32 + quad * 8];
#pragma unroll
    for (int ni = 0; ni < 4; ni++)
      bfr[ni] = *(const bf16x8*)&lB[cur][(wn * 64 + ni * 16 + l16) * 32 + quad * 8];
#pragma unroll
    for (int mi = 0; mi < 4; mi++)
#pragma unroll
      for (int ni = 0; ni < 4; ni++)
        acc[mi][ni] = MFMA16(af[mi], bfr[ni], acc[mi][ni]);
    cur ^= 1;
  }

#pragma unroll
  for (int mi = 0; mi < 4; mi++) {
#pragma unroll
    for (int ni = 0; ni < 4; ni++) {
#pragma unroll
      for (int r = 0; r < 4; r++) {
        const long row = m0 + wm * 64 + mi * 16 + quad * 4 + r;
        const long col = n0 + wn * 64 + ni * 16 + l16;
        const long idx = row * N + col;
        float v = acc[mi][ni][r];
        if (EPI == 0) {
          ((__hip_bfloat16*)Cv)[idx] = __float2bfloat16(v);
        } else if (EPI == 1) {
          ((float*)Cv)[idx] = v + res[idx];
        } else if (EPI == 2) {
          v += bias[col];
          ((__hip_bfloat16*)Cv)[idx] = __float2bfloat16(fmaxf(v, 0.f));
        } else if (EPI == 3) {
          float* Cf = (float*)Cv;
          Cf[idx] = Cf[idx] + v;
        }
      }
    }
  }
}

// ---------------------------------------------------------------------------
// 128x128 tile, BK=64, XOR-swizzled LDS (round 7). Used for ffn1 only.
// ---------------------------------------------------------------------------
template <int EPI>
__global__ __launch_bounds__(256) void gemm_bt_k64_kernel(
    const __hip_bfloat16* __restrict__ A, const __hip_bfloat16* __restrict__ Bt,
    void* __restrict__ Cv, const float* __restrict__ bias,
    const float* __restrict__ res, int M, int N, int K) {
  __shared__ __align__(16) __hip_bfloat16 lA[2][128 * 64];
  __shared__ __align__(16) __hip_bfloat16 lB[2][128 * 64];
  const int tid = threadIdx.x;
  const int wave = tid >> 6, lane = tid & 63;
  const int quad = lane >> 4, l16 = lane & 15;
  const int wm = wave >> 1, wn = wave & 1;

  const int gx = gridDim.x;
  const int nwg = gx * gridDim.y;
  int bid = blockIdx.y * gx + blockIdx.x;
  bid = (bid & 7) * (nwg >> 3) + (bid >> 3);
  const long m0 = (long)(bid / gx) * 128;
  const long n0 = (long)(bid % gx) * 128;

  const int srow = lane >> 3;               // row within 8-row chunk
  const int cg = (lane & 7) ^ srow;         // pre-swizzled global k-group

  floatx4 acc[4][4];
#pragma unroll
  for (int i = 0; i < 4; i++)
#pragma unroll
    for (int j = 0; j < 4; j++) acc[i][j] = (floatx4){0.f, 0.f, 0.f, 0.f};

  const __hip_bfloat16* Ab = A + m0 * K;
  const __hip_bfloat16* Bb = Bt + n0 * K;

#pragma unroll
  for (int j = 0; j < 4; ++j) {
    const int c = wave + j * 4;
    gll16(&Ab[(long)(c * 8 + srow) * K + cg * 8], &lA[0][c * 512]);
    gll16(&Bb[(long)(c * 8 + srow) * K + cg * 8], &lB[0][c * 512]);
  }

  int cur = 0;
  for (int k0 = 0; k0 < K; k0 += 64) {
    __syncthreads();
    if (k0 + 64 < K) {
      const int nxt = cur ^ 1;
#pragma unroll
      for (int j = 0; j < 4; ++j) {
        const int c = wave + j * 4;
        gll16(&Ab[(long)(c * 8 + srow) * K + k0 + 64 + cg * 8], &lA[nxt][c * 512]);
        gll16(&Bb[(long)(c * 8 + srow) * K + k0 + 64 + cg * 8], &lB[nxt][c * 512]);
      }
    }
#pragma unroll
    for (int ks = 0; ks < 2; ++ks) {
      bf16x8 af[4], bfr[4];
#pragma unroll
      for (int mi = 0; mi < 4; mi++) {
        const int row = wm * 64 + mi * 16 + l16;
        af[mi] = *(const bf16x8*)&lA[cur][row * 64 +
                                          (((ks * 4 + quad) ^ (l16 & 7)) * 8)];
      }
#pragma unroll
      for (int ni = 0; ni < 4; ni++) {
        const int row = wn * 64 + ni * 16 + l16;
        bfr[ni] = *(const bf16x8*)&lB[cur][row * 64 +
                                           (((ks * 4 + quad) ^ (l16 & 7)) * 8)];
      }
#pragma unroll
      for (int mi = 0; mi < 4; mi++)
#pragma unroll
        for (int ni = 0; ni < 4; ni++)
          acc[mi][ni] = MFMA16(af[mi], bfr[ni], acc[mi][ni]);
    }
    cur ^= 1;
  }

#pragma unroll
  for (int mi = 0; mi < 4; mi++) {
#pragma unroll
    for (int ni = 0; ni < 4; ni++) {
#pragma unroll
      for (int r = 0; r < 4; r++) {
        const long row = m0 + wm * 64 + mi * 16 + quad * 4 + r;
        const long col = n0 + wn * 64 + ni * 16 + l16;
        const long idx = row * N + col;
        float v = acc[mi][ni][r];
        if (EPI == 0) {
          ((__hip_bfloat16*)Cv)[idx] = __float2bfloat16(v);
        } else if (EPI == 1) {
          ((float*)Cv)[idx] = v + res[idx];
        } else if (EPI == 2) {
          v += bias[col];
          ((__hip_bfloat16*)Cv)[idx] = __float2bfloat16(fmaxf(v, 0.f));
        } else if (EPI == 3) {
          float* Cf = (float*)Cv;
          Cf[idx] = Cf[idx] + v;
        }
      }
    }
  }
}

// ---------------------------------------------------------------------------
// 128x64-tile variant for N=1024 GEMMs (wo, ffn2): BK=64 swizzled (round 6).
// ---------------------------------------------------------------------------
template <int EPI>
__global__ __launch_bounds__(256) void gemm64_bt_kernel(
    const __hip_bfloat16* __restrict__ A, const __hip_bfloat16* __restrict__ Bt,
    void* __restrict__ Cv, const float* __restrict__ bias,
    const float* __restrict__ res, int M, int N, int K) {
  __shared__ __align__(16) __hip_bfloat16 lA[2][128 * 64];
  __shared__ __align__(16) __hip_bfloat16 lB[2][64 * 64];
  const int tid = threadIdx.x;
  const int wave = tid >> 6, lane = tid & 63;
  const int quad = lane >> 4, l16 = lane & 15;
  const int wm = wave >> 1, wn = wave & 1;

  const int gx = gridDim.x;
  const int nwg = gx * gridDim.y;
  int bid = blockIdx.y * gx + blockIdx.x;
  bid = (bid & 7) * (nwg >> 3) + (bid >> 3);
  const long m0 = (long)(bid / gx) * 128;
  const long n0 = (long)(bid % gx) * 64;

  const int srow = lane >> 3;
  const int cg = (lane & 7) ^ srow;

  floatx4 acc[4][2];
#pragma unroll
  for (int i = 0; i < 4; i++)
#pragma unroll
    for (int j = 0; j < 2; j++) acc[i][j] = (floatx4){0.f, 0.f, 0.f, 0.f};

  const __hip_bfloat16* Ab = A + m0 * K;
  const __hip_bfloat16* Bb = Bt + n0 * K;

#pragma unroll
  for (int j = 0; j < 4; ++j) {
    const int c = wave + j * 4;
    gll16(&Ab[(long)(c * 8 + srow) * K + cg * 8], &lA[0][c * 512]);
  }
#pragma unroll
  for (int j = 0; j < 2; ++j) {
    const int c = wave + j * 4;
    gll16(&Bb[(long)(c * 8 + srow) * K + cg * 8], &lB[0][c * 512]);
  }

  int cur = 0;
  for (int k0 = 0; k0 < K; k0 += 64) {
    __syncthreads();
    if (k0 + 64 < K) {
      const int nxt = cur ^ 1;
#pragma unroll
      for (int j = 0; j < 4; ++j) {
        const int c = wave + j * 4;
        gll16(&Ab[(long)(c * 8 + srow) * K + k0 + 64 + cg * 8], &lA[nxt][c * 512]);
      }
#pragma unroll
      for (int j = 0; j < 2; ++j) {
        const int c = wave + j * 4;
        gll16(&Bb[(long)(c * 8 + srow) * K + k0 + 64 + cg * 8], &lB[nxt][c * 512]);
      }
    }
#pragma unroll
    for (int ks = 0; ks < 2; ++ks) {
      bf16x8 af[4], bfr[2];
#pragma unroll
      for (int mi = 0; mi < 4; mi++) {
        const int row = wm * 64 + mi * 16 + l16;
        af[mi] = *(const bf16x8*)&lA[cur][row * 64 +
                                          (((ks * 4 + quad) ^ (l16 & 7)) * 8)];
      }
#pragma unroll
      for (int ni = 0; ni < 2; ni++) {
        const int row = wn * 32 + ni * 16 + l16;
        bfr[ni] = *(const bf16x8*)&lB[cur][row * 64 +
                                           (((ks * 4 + quad) ^ (l16 & 7)) * 8)];
      }
#pragma unroll
      for (int mi = 0; mi < 4; mi++)
#pragma unroll
        for (int ni = 0; ni < 2; ni++)
          acc[mi][ni] = MFMA16(af[mi], bfr[ni], acc[mi][ni]);
    }
    cur ^= 1;
  }

#pragma unroll
  for (int mi = 0; mi < 4; mi++) {
#pragma unroll
    for (int ni = 0; ni < 2; ni++) {
#pragma unroll
      for (int r = 0; r < 4; r++) {
        const long row = m0 + wm * 64 + mi * 16 + quad * 4 + r;
        const long col = n0 + wn * 32 + ni * 16 + l16;
        const long idx = row * N + col;
        float v = acc[mi][ni][r];
        if (EPI == 1) {
          ((float*)Cv)[idx] = v + res[idx];
        } else if (EPI == 3) {
          float* Cf = (float*)Cv;
          Cf[idx] = Cf[idx] + v;
        }
      }
    }
  }
}

// ---------------------------------------------------------------------------
// Flash attention — round 9 version restored byte-for-byte (74 us; the r10
// T15 PV-delay regressed to 94.6 us: lP RAW dependency serialized the
// intended overlap and 48 KB LDS cut occupancy 4->3 blocks/CU). 64 q-rows/
// block, 2-buffer K/V dbuf, single wave-private lP, speculative softmax with
// post-PV fixup, XCD-chunked swizzle (FETCH 69.7 -> 12.3 MB).
// Attn ledger: r8 q-doubling neutral; r10 PV-delay negative — this structure
// is a verified local optimum; do not graft single T-techniques onto it.
// ---------------------------------------------------------------------------
__global__ __launch_bounds__(256) void attn_kernel(
    const __hip_bfloat16* __restrict__ qkv, const __hip_bfloat16* __restrict__ vt,
    const float* __restrict__ addm, const int* __restrict__ flags,
    __hip_bfloat16* __restrict__ ctx) {
  __shared__ __align__(16) __hip_bfloat16 lK[2][64 * 64];
  __shared__ __align__(16) __hip_bfloat16 lV[2][64 * 64];
  __shared__ __align__(16) __hip_bfloat16 lP[4][16 * 64];  // wave-private P^T
  const int tid = threadIdx.x, wave = tid >> 6, lane = tid & 63;
  const int quad = lane >> 4, l16 = lane & 15;
  // XCD-chunked swizzle over the flat 1024-block grid
  const int nwg = gridDim.x * gridDim.y;
  int bid0 = blockIdx.y * gridDim.x + blockIdx.x;
  bid0 = (bid0 & 7) * (nwg >> 3) + (bid0 >> 3);
  const int bh = bid0 >> 5, b = bh >> 4, h = bh & 15;
  const int q0 = (bid0 & 31) * 64 + wave * 16;
  const float cs = 0.18033688011112042f;   // log2(e)/sqrt(64)
  const float inv_cs = 5.545177444479562f; // sqrt(64)/log2(e)

  const __hip_bfloat16* kb = qkv + (long)b * 2048 * 3072 + 1024 + h * 64;
  const __hip_bfloat16* vb = vt + (long)bh * 64 * 2048;
  const float* am = addm + b * 2048;

  int fm = 1;
#pragma unroll
  for (int i = 0; i < 8; ++i) fm &= flags[b * 8 + i];
  const bool fast = (fm != 0);

  const long qoff = ((long)b * 2048 + q0 + l16) * 3072 + h * 64;
  const bf16x8 bq0 = *(const bf16x8*)&qkv[qoff + quad * 8];
  const bf16x8 bq1 = *(const bf16x8*)&qkv[qoff + 32 + quad * 8];

  const int srow = lane >> 3;
  const int cslot = lane & 7;
  const int cg = cslot ^ srow;
  const int rbase = wave * 16 + srow;

  // P-buffer addresses (bytes within this wave's 2 KB region)
  char* const pbase = (char*)&lP[wave][0];
  const int prow = l16 * 128;
  const int pswz = l16 & 7;

  floatx4 o[4];
#pragma unroll
  for (int mi = 0; mi < 4; mi++) o[mi] = (floatx4){0.f, 0.f, 0.f, 0.f};
  float mrow = 10.0f, lrow = 0.f;  // mrow in log2 units (score*cs domain)

  // prologue: stage tile 0 into buffer 0
#pragma unroll
  for (int j = 0; j < 2; ++j) {
    const int rloc = rbase + j * 8;
    gll16(kb + (long)rloc * 3072 + cg * 8, &lK[0][(wave * 16 + j * 8) * 64]);
    gll16(vb + (long)rloc * 2048 + cg * 8, &lV[0][(wave * 16 + j * 8) * 64]);
  }

  int cur = 0;
  for (int t = 0; t < 32; ++t) {
    __syncthreads();
    if (t + 1 < 32) {
      const int nxt = cur ^ 1;
#pragma unroll
      for (int j = 0; j < 2; ++j) {
        const int rloc = rbase + j * 8;
        gll16(kb + (long)((t + 1) * 64 + rloc) * 3072 + cg * 8,
              &lK[nxt][(wave * 16 + j * 8) * 64]);
        gll16(vb + (long)rloc * 2048 + (t + 1) * 64 + cg * 8,
              &lV[nxt][(wave * 16 + j * 8) * 64]);
      }
    }
    const __hip_bfloat16* lKc = lK[cur];
    const __hip_bfloat16* lVc = lV[cur];

    floatx4 c[4];
    __builtin_amdgcn_s_setprio(1);
#pragma unroll
    for (int g = 0; g < 4; ++g) {
      const bf16x8 a0 =
          *(const bf16x8*)&lKc[(g * 16 + l16) * 64 + ((quad) ^ (l16 & 7)) * 8];
      const bf16x8 a1 =
          *(const bf16x8*)&lKc[(g * 16 + l16) * 64 + ((4 + quad) ^ (l16 & 7)) * 8];
      floatx4 cc = {0.f, 0.f, 0.f, 0.f};
      cc = MFMA16(a0, bq0, cc);
      cc = MFMA16(a1, bq1, cc);
      c[g] = cc;
    }
    __builtin_amdgcn_s_setprio(0);

    if (!fast) {
#pragma unroll
      for (int g = 0; g < 4; ++g) {
        const float4 a4 = *(const float4*)&am[t * 64 + g * 16 + quad * 4];
        c[g][0] = fmaf(a4.x, inv_cs, c[g][0]);
        c[g][1] = fmaf(a4.y, inv_cs, c[g][1]);
        c[g][2] = fmaf(a4.z, inv_cs, c[g][2]);
        c[g][3] = fmaf(a4.w, inv_cs, c[g][3]);
      }
    }

    // speculative P with the OLD running max — off the max-reduce chain
    const float mneg = -mrow;
    float p[4][4];
#pragma unroll
    for (int g = 0; g < 4; ++g)
#pragma unroll
      for (int r = 0; r < 4; ++r)
        p[g][r] = __builtin_amdgcn_exp2f(fmaf(c[g][r], cs, mneg));

    // pack P and write to the wave-private LDS transpose buffer.
#pragma unroll
    for (int g = 0; g < 4; ++g) {
      uint2 w2;
      w2.x = cvtpk(p[g][0], p[g][1]);
      w2.y = cvtpk(p[g][2], p[g][3]);
      const int slot16 = (g * 2 + (quad >> 1)) ^ pswz;
      *(uint2*)(pbase + prow + (slot16 << 4) + ((quad & 1) << 3)) = w2;
    }

    // tile row-max reduce — concurrent with PV below
    const float m0 = fmaxf(fmaxf(c[0][0], c[0][1]), c[0][2]);
    const float m1 = fmaxf(fmaxf(c[0][3], c[1][0]), c[1][1]);
    const float m2 = fmaxf(fmaxf(c[1][2], c[1][3]), c[2][0]);
    const float m3 = fmaxf(fmaxf(c[2][1], c[2][2]), c[2][3]);
    const float m4 = fmaxf(fmaxf(c[3][0], c[3][1]), c[3][2]);
    float tm = fmaxf(fmaxf(fmaxf(m0, m1), fmaxf(m2, m3)), fmaxf(m4, c[3][3]));
    tm = fmaxf(tm, __shfl_xor(tm, 16));
    tm = fmaxf(tm, __shfl_xor(tm, 32));
    const float tms = tm * cs;

    const float s0 = (p[0][0] + p[0][1]) + (p[0][2] + p[0][3]);
    const float s1 = (p[1][0] + p[1][1]) + (p[1][2] + p[1][3]);
    const float s2 = (p[2][0] + p[2][1]) + (p[2][2] + p[2][3]);
    const float s3 = (p[3][0] + p[3][1]) + (p[3][2] + p[3][3]);
    float rs = (s0 + s1) + (s2 + s3);
    rs += __shfl_xor(rs, 16);
    rs += __shfl_xor(rs, 32);

    // PV: B-fragment = one swizzled b128 from the wave P-buffer
#pragma unroll
    for (int ss = 0; ss < 2; ++ss) {
      const bf16x8 bp = *(const bf16x8*)(pbase + prow +
                                         ((((ss << 2) + quad) ^ pswz) << 4));
      __builtin_amdgcn_s_setprio(1);
#pragma unroll
      for (int mi = 0; mi < 4; ++mi) {
        const bf16x8 av = *(const bf16x8*)&lVc[(mi * 16 + l16) * 64 +
                                               ((ss * 4 + quad) ^ (l16 & 7)) * 8];
        o[mi] = MFMA16(av, bp, o[mi]);
      }
      __builtin_amdgcn_s_setprio(0);
    }

    lrow += rs;
    if (__any(tms > mrow + 8.f)) {
      const float mnew = fmaxf(mrow, tms);
      const float alpha = __builtin_amdgcn_exp2f(mrow - mnew);
      mrow = mnew;
      lrow *= alpha;
#pragma unroll
      for (int mi = 0; mi < 4; mi++) o[mi] *= alpha;
    }
    cur ^= 1;
  }

  const float inv_l = 1.f / lrow;
  const long cb = ((long)b * 2048 + q0 + l16) * 1024 + h * 64;
#pragma unroll
  for (int mi = 0; mi < 4; mi++) {
    uint2 st;
    st.x = cvtpk(o[mi][0] * inv_l, o[mi][1] * inv_l);
    st.y = cvtpk(o[mi][2] * inv_l, o[mi][3] * inv_l);
    *(uint2*)&ctx[cb + mi * 16 + quad * 4] = st;
  }
}

// ---------------------------------------------------------------------------
// ws plan (peak 32 MiB) + d_out (16 MiB) as scratch:
//  A: ln_qkvtrans (1792 blocks): ln1 x->xn(d_out[0,8)) + wqkvT ws[24,30);
//     qkv-gemm (BK=32) -> qkv ws[0,24)
//  B: prep: vtrans -> vtb ws[24,32); woT -> d_out[8,10); mask -> addm+flags;
//     attn (r9 version, XCD-swizzled) -> ctxb(d_out[0,8))
//  C: wo-gemm64(ctxb,woT)+x -> x1 f32 ws[0,16)  (EPI1)
//  D: ln2_wtrans (2048 blocks): ln2 x1->xn2(d_out[0,8)) + wtrans(c=0)
//  E: ffn1-k64(c=0) -> hc ws[16,32); ffn2-gemm64(c=0): x1 += (EPI3);
//     wtrans(c=1); ffn1-k64(c=1); ffn2-gemm64(c=1)
//  F: bias_add: d_out = x1 + b2
//  12 launches.
// ---------------------------------------------------------------------------
extern "C" void kernel_launch(void* const* d_in, const int* in_sizes, int n_in,
                              void* d_out, int out_size, void* d_ws, size_t ws_size,
                              hipStream_t stream) {
  const float* x = (const float*)d_in[0];
  const int* mask = (const int*)d_in[1];
  const float* wq = (const float*)d_in[2];
  const float* wk = (const float*)d_in[3];
  const float* wv = (const float*)d_in[4];
  const float* wo = (const float*)d_in[5];
  const float* w1 = (const float*)d_in[6];
  const float* b1 = (const float*)d_in[7];
  const float* w2 = (const float*)d_in[8];
  const float* b2 = (const float*)d_in[9];
  const float* alpha1 = (const float*)d_in[10];
  const float* bias1 = (const float*)d_in[11];
  const float* alpha2 = (const float*)d_in[12];
  const float* bias2 = (const float*)d_in[13];

  char* ws = (char*)d_ws;
  char* dob = (char*)d_out;
  const size_t MiB = 1048576;
  __hip_bfloat16* qkv   = (__hip_bfloat16*)(ws + 0);          // [0,24)
  __hip_bfloat16* wqkvT = (__hip_bfloat16*)(ws + 24 * MiB);   // [24,30)
  __hip_bfloat16* vtb   = (__hip_bfloat16*)(ws + 24 * MiB);   // [24,32)
  float*          x1    = (float*)(ws + 0);                   // [0,16) f32
  __hip_bfloat16* hc    = (__hip_bfloat16*)(ws + 16 * MiB);   // [16,32)
  __hip_bfloat16* xn    = (__hip_bfloat16*)d_out;             // d_out[0,8) bf16
  __hip_bfloat16* ctxb  = (__hip_bfloat16*)d_out;
  __hip_bfloat16* xn2   = (__hip_bfloat16*)d_out;
  __hip_bfloat16* woT   = (__hip_bfloat16*)(dob + 8 * MiB);   // d_out[8,10)
  __hip_bfloat16* w1Th  = (__hip_bfloat16*)(dob + 8 * MiB);   // d_out[8,12)
  __hip_bfloat16* w2Th  = (__hip_bfloat16*)(dob + 12 * MiB);  // d_out[12,16)
  float*          addm  = (float*)(dob + 12 * MiB);           // d_out[12M,+16K)
  int*            flags = (int*)(dob + 12 * MiB + 16 * 1024); // 64 B after addm

  const dim3 b256(256);
  // Stage A
  ln_qkvtrans_kernel<<<1792, b256, 0, stream>>>(x, xn, alpha1, bias1,
                                                wq, wk, wv, wqkvT);
  gemm_bt_kernel<0><<<dim3(24, 32), b256, 0, stream>>>(xn, wqkvT, qkv, nullptr,
                                                       nullptr, 4096, 3072, 1024);
  // Stage B
  prep_kernel<<<1296, b256, 0, stream>>>(qkv, vtb, wo, woT, mask, addm, flags);
  attn_kernel<<<dim3(32, 32), b256, 0, stream>>>(qkv, vtb, addm, flags, ctxb);
  // Stage C
  gemm64_bt_kernel<1><<<dim3(16, 32), b256, 0, stream>>>(ctxb, woT, x1, nullptr, x,
                                                         4096, 1024, 1024);
  // Stage D (merged ln2 + wtrans c=0)
  ln2_wtrans_kernel<<<2048, b256, 0, stream>>>(x1, xn2, alpha2, bias2,
                                               w1, w2, w1Th, w2Th);
  // Stage E
  gemm_bt_k64_kernel<2><<<dim3(16, 32), b256, 0, stream>>>(xn2, w1Th, hc,
                                                           b1, nullptr,
                                                           4096, 2048, 1024);
  gemm64_bt_kernel<3><<<dim3(16, 32), b256, 0, stream>>>(hc, w2Th, x1, nullptr,
                                                         nullptr, 4096, 1024, 2048);
  wtrans_kernel<<<1024, b256, 0, stream>>>(w1 + 2048,
                                           w2 + (size_t)2048 * 1024,
                                           w1Th, w2Th);
  gemm_bt_k64_kernel<2><<<dim3(16, 32), b256, 0, stream>>>(xn2, w1Th, hc,
                                                           b1 + 2048, nullptr,
                                                           4096, 2048, 1024);
  gemm64_bt_kernel<3><<<dim3(16, 32), b256, 0, stream>>>(hc, w2Th, x1, nullptr,
                                                         nullptr, 4096, 1024, 2048);
  // Stage F
  bias_add_kernel<<<4096, b256, 0, stream>>>(x1, b2, (float*)d_out);
}